// Round 4
// baseline (304.633 us; speedup 1.0000x reference)
//
#include <hip/hip_runtime.h>

// out = irfft2( rfft2(x_grid) * W ), ortho, grid 16x16, C=768, B=256.
// Per block (b, 32 channels), 256 threads, 3 stages through one 16.5KB LDS
// buffer holding inter-stage spectra as packed f16 pairs (fp32 compute).
//  S1: per (i, ch-pair): 2 channels ride as re/im of one fft16 over j ->
//      half-spectra k2=0..8 (k2 in {0,8} real, packed into slot 0).
//  S2: per (k2-slot, ch): fft16 over i, weight multiply (norms folded),
//      ifft16 over k1 -> n1. Slot 0 handles k2=0&8 via folded weights.
//  S3: per (n1, ch-pair): Hermitian-extend 2 channels as one complex ifft16
//      over k2 -> n2, store real pair coalesced.

#define DIM 768
#define CT 32
#define NCT (DIM / CT)   // 24
#define IP 258           // half2-entry pitch per i-row: 8 slots * 32 ch + 2 pad

#define R2c  0.70710678118654752f
#define C1c  0.92387953251128674f
#define S1cc 0.38268343236508978f
#define INV512  (1.f / 512.f)
#define INV256  (1.f / 256.f)
#define INV1024 (1.f / 1024.f)

typedef __fp16 h2v __attribute__((ext_vector_type(2)));
union H2U { h2v h; uint32_t u; };

__device__ __forceinline__ uint32_t packh2(float a, float b) {
  H2U t; t.h = __builtin_amdgcn_cvt_pkrtz(a, b); return t.u;
}
__device__ __forceinline__ float2 unpackh2(uint32_t v) {
  H2U t; t.u = v; return make_float2((float)t.h.x, (float)t.h.y);
}

template <int SGN>   // SGN = -1 forward, +1 inverse (unnormalized)
__device__ __forceinline__ void fft16(float* xr, float* xi) {
#define SWP(a, b) { float t_ = xr[a]; xr[a] = xr[b]; xr[b] = t_; t_ = xi[a]; xi[a] = xi[b]; xi[b] = t_; }
  SWP(1, 8) SWP(2, 4) SWP(3, 12) SWP(5, 10) SWP(7, 14) SWP(11, 13)
#undef SWP
#define BF1(a, b) { float tr = xr[b], ti = xi[b]; xr[b] = xr[a] - tr; xi[b] = xi[a] - ti; xr[a] += tr; xi[a] += ti; }
#define BFI(a, b) { float tr, ti; if (SGN < 0) { tr = xi[b]; ti = -xr[b]; } else { tr = -xi[b]; ti = xr[b]; } \
                    xr[b] = xr[a] - tr; xi[b] = xi[a] - ti; xr[a] += tr; xi[a] += ti; }
#define BFW(a, b, Wr, Wi) { float tr = (Wr) * xr[b] - (Wi) * xi[b], ti = (Wr) * xi[b] + (Wi) * xr[b]; \
                            xr[b] = xr[a] - tr; xi[b] = xi[a] - ti; xr[a] += tr; xi[a] += ti; }
  BF1(0, 1) BF1(2, 3) BF1(4, 5) BF1(6, 7) BF1(8, 9) BF1(10, 11) BF1(12, 13) BF1(14, 15)
  BF1(0, 2) BF1(4, 6) BF1(8, 10) BF1(12, 14)
  BFI(1, 3) BFI(5, 7) BFI(9, 11) BFI(13, 15)
  BF1(0, 4) BF1(8, 12)
  BFW(1, 5, R2c, SGN * R2c) BFW(9, 13, R2c, SGN * R2c)
  BFI(2, 6) BFI(10, 14)
  BFW(3, 7, -R2c, SGN * R2c) BFW(11, 15, -R2c, SGN * R2c)
  BF1(0, 8)
  BFW(1, 9, C1c, SGN * S1cc)
  BFW(2, 10, R2c, SGN * R2c)
  BFW(3, 11, S1cc, SGN * C1c)
  BFI(4, 12)
  BFW(5, 13, -S1cc, SGN * C1c)
  BFW(6, 14, -R2c, SGN * R2c)
  BFW(7, 15, -C1c, SGN * S1cc)
#undef BF1
#undef BFI
#undef BFW
}

__global__ __launch_bounds__(256, 8) void gf3_kernel(const float* __restrict__ x,
                                                     const float* __restrict__ w,
                                                     float* __restrict__ out) {
  __shared__ __align__(8) uint32_t E[16 * IP];   // 16.5 KB, U then aliased as Q

  const int blk = blockIdx.x;
  const int ct = blk >> 8;        // 0..23  (ct-outer: W slice L2-hot)
  const int b  = blk & 255;
  const int c0 = ct * CT;
  const int t  = threadIdx.x;
  const int r  = t >> 4;          // i (S1) / n1 (S3)
  const int p  = t & 15;          // channel-pair index

  // ---------------- S1: rfft over j, 2 channels packed ----------------
  {
    const float2* xp = (const float2*)(x + (size_t)b * 196608 + (size_t)r * 12288 + c0) + p;
    float zr[16], zi[16];
#pragma unroll
    for (int j = 0; j < 16; j++) { float2 v = xp[j * 384]; zr[j] = v.x; zi[j] = v.y; }
    fft16<-1>(zr, zi);
    // slot 0: (F_a[0], F_a[8]) , (F_b[0], F_b[8])  (1x scale)
    {
      uint2 v; v.x = packh2(zr[0], zr[8]); v.y = packh2(zi[0], zi[8]);
      *(uint2*)&E[2 * (r * 129 + p)] = v;
    }
    // slots k=1..7: doubled half-spectra A'=2*F_a, B'=2*F_b
#pragma unroll
    for (int k = 1; k <= 7; k++) {
      const int m = 16 - k;
      float Ar = zr[k] + zr[m], Ai = zi[k] - zi[m];
      float Br = zi[k] + zi[m], Bi = zr[m] - zr[k];
      uint2 v; v.x = packh2(Ar, Ai); v.y = packh2(Br, Bi);
      *(uint2*)&E[2 * (r * 129 + k * 16 + p)] = v;
    }
  }
  __syncthreads();

  // ---------------- S2: fft over i, weight, ifft over k1 ----------------
  {
    const int s = t >> 5;         // slot 0..7
    const int c = t & 31;         // channel within tile
    float gr[16], gi[16];
    const uint32_t* col = E + s * 32 + c;
#pragma unroll
    for (int i = 0; i < 16; i++) { float2 v = unpackh2(col[i * IP]); gr[i] = v.x; gi[i] = v.y; }
    __syncthreads();              // all reads of U done before Q overwrites

    if (s == 0) {
      // packed: columns k2=0 and k2=8 (real), folded weights
      fft16<-1>(gr, gi);
      const float* wc = w + (size_t)(c0 + c) * 2;   // per-k1 stride 13824 floats; +12288 for k2=8
      {
        float2 a0 = *(const float2*)(wc);
        float2 a8 = *(const float2*)(wc + 12288);
        float2 b0 = *(const float2*)(wc + 8 * 13824);
        float2 b8 = *(const float2*)(wc + 8 * 13824 + 12288);
        gr[0] = gr[0] * (a0.x * INV256);
        gi[0] = gi[0] * (a8.x * INV256);
        gr[8] = gr[8] * (b0.x * INV256);
        gi[8] = gi[8] * (b8.x * INV256);
      }
#pragma unroll
      for (int k = 1; k <= 7; k++) {
        const int m = 16 - k;
        float2 a0 = *(const float2*)(wc + (size_t)k * 13824);
        float2 m0 = *(const float2*)(wc + (size_t)m * 13824);
        float2 a8 = *(const float2*)(wc + (size_t)k * 13824 + 12288);
        float2 m8 = *(const float2*)(wc + (size_t)m * 13824 + 12288);
        float Vpr = (a0.x + m0.x + a8.x + m8.x) * INV1024;
        float Vpi = (a0.y - m0.y + a8.y - m8.y) * INV1024;
        float Vmr = (a0.x + m0.x - a8.x - m8.x) * INV1024;
        float Vmi = (a0.y - m0.y - a8.y + m8.y) * INV1024;
        float ur = gr[k], ui = gi[k], vr = gr[m], vi = gi[m];
        float nkr = ur * Vpr - ui * Vpi + vr * Vmr + vi * Vmi;
        float nki = ur * Vpi + ui * Vpr + vr * Vmi - vi * Vmr;
        float nmr = vr * Vpr + vi * Vpi + ur * Vmr - ui * Vmi;
        float nmi = vi * Vpr - vr * Vpi - ur * Vmi - ui * Vmr;
        gr[k] = nkr; gi[k] = nki; gr[m] = nmr; gi[m] = nmi;
      }
      fft16<1>(gr, gi);           // (re, im) = (Re Q[.][0], Re Q[.][8])
    } else {
      // regular: column k2 = s (stored doubled -> weight * 1/512)
      float wvr[16], wvi[16];
      const float* wp = w + (size_t)(s * 768 + c0 + c) * 2;
#pragma unroll
      for (int k1 = 0; k1 < 16; k1++) {
        float2 wv = *(const float2*)(wp + (size_t)k1 * 13824);
        wvr[k1] = wv.x * INV512; wvi[k1] = wv.y * INV512;
      }
      fft16<-1>(gr, gi);
#pragma unroll
      for (int k1 = 0; k1 < 16; k1++) {
        float yr = gr[k1] * wvr[k1] - gi[k1] * wvi[k1];
        float yi = gr[k1] * wvi[k1] + gi[k1] * wvr[k1];
        gr[k1] = yr; gi[k1] = yi;
      }
      fft16<1>(gr, gi);
    }

    uint32_t* colo = E + s * 32 + c;
#pragma unroll
    for (int n1 = 0; n1 < 16; n1++) { colo[n1 * IP] = packh2(gr[n1], gi[n1]); }
  }
  __syncthreads();

  // ---------------- S3: irfft over k2, 2 channels packed, store ----------------
  {
    float hr[16], hq[16];
#pragma unroll
    for (int k = 0; k <= 7; k++) {
      uint2 v = *(const uint2*)&E[2 * (r * 129 + k * 16 + p)];
      float2 lo = unpackh2(v.x);   // (a.re, a.im)  /  k=0: (Q0_a, Q8_a)
      float2 hi = unpackh2(v.y);   // (b.re, b.im)  /  k=0: (Q0_b, Q8_b)
      if (k == 0) {
        hr[0] = lo.x; hq[0] = hi.x;
        hr[8] = lo.y; hq[8] = hi.y;
      } else {
        hr[k] = lo.x - hi.y;      hq[k] = lo.y + hi.x;
        hr[16 - k] = lo.x + hi.y; hq[16 - k] = hi.x - lo.y;
      }
    }
    fft16<1>(hr, hq);   // (re, im) = (out_a[n2], out_b[n2])
    float2* op = (float2*)(out + (size_t)b * 196608 + (size_t)r * 12288 + c0) + p;
#pragma unroll
    for (int n2 = 0; n2 < 16; n2++) { op[n2 * 384] = make_float2(hr[n2], hq[n2]); }
  }
}

extern "C" void kernel_launch(void* const* d_in, const int* in_sizes, int n_in,
                              void* d_out, int out_size, void* d_ws, size_t ws_size,
                              hipStream_t stream) {
  const float* x = (const float*)d_in[0];
  const float* w = (const float*)d_in[1];
  float* out = (float*)d_out;
  dim3 grid(NCT * 256);   // 24 * 256 = 6144
  dim3 block(256);
  hipLaunchKernelGGL(gf3_kernel, grid, block, 0, stream, x, w, out);
}

// Round 5
// 112.743 us; speedup vs baseline: 2.7020x; 2.7020x over previous
//
#include <hip/hip_runtime.h>

// out = irfft2( rfft2(x_grid) * W ), ortho, grid 16x16, C=768, B=256.
// Per block (b, 32 channels), 256 threads, 3 stages through one 16.5KB LDS
// buffer holding inter-stage spectra as packed f16 pairs (fp32 compute).
//  S1: per (i, ch-pair): 2 channels ride as re/im of one fft16 over j ->
//      half-spectra k2=0..8 (k2 in {0,8} real, packed into slot 0).
//  S2: per (k2-slot, ch): fft16 over i, weight multiply (norms folded),
//      ifft16 over k1 -> n1. Slot 0 handles k2=0&8 via folded weights.
//  S3: per (n1, ch-pair): Hermitian-extend 2 channels as one complex ifft16
//      over k2 -> n2, store real pair coalesced.
// NOTE: launch_bounds(256,4) — (256,8) caps VGPR at 32 and spills ~600MB/launch
// to scratch (R4: hbm_bytes 1.15GB, dur 304us). 64 VGPR + 16.9KB LDS already
// lets HW run 8 blocks/CU without the cap.

#define DIM 768
#define CT 32
#define NCT (DIM / CT)   // 24
#define IP 258           // half2-entry pitch per i-row: 8 slots * 32 ch + 2 pad

#define R2c  0.70710678118654752f
#define C1c  0.92387953251128674f
#define S1cc 0.38268343236508978f
#define INV512  (1.f / 512.f)
#define INV256  (1.f / 256.f)
#define INV1024 (1.f / 1024.f)

typedef __fp16 h2v __attribute__((ext_vector_type(2)));
union H2U { h2v h; uint32_t u; };

__device__ __forceinline__ uint32_t packh2(float a, float b) {
  H2U t; t.h = __builtin_amdgcn_cvt_pkrtz(a, b); return t.u;
}
__device__ __forceinline__ float2 unpackh2(uint32_t v) {
  H2U t; t.u = v; return make_float2((float)t.h.x, (float)t.h.y);
}

template <int SGN>   // SGN = -1 forward, +1 inverse (unnormalized)
__device__ __forceinline__ void fft16(float* xr, float* xi) {
#define SWP(a, b) { float t_ = xr[a]; xr[a] = xr[b]; xr[b] = t_; t_ = xi[a]; xi[a] = xi[b]; xi[b] = t_; }
  SWP(1, 8) SWP(2, 4) SWP(3, 12) SWP(5, 10) SWP(7, 14) SWP(11, 13)
#undef SWP
#define BF1(a, b) { float tr = xr[b], ti = xi[b]; xr[b] = xr[a] - tr; xi[b] = xi[a] - ti; xr[a] += tr; xi[a] += ti; }
#define BFI(a, b) { float tr, ti; if (SGN < 0) { tr = xi[b]; ti = -xr[b]; } else { tr = -xi[b]; ti = xr[b]; } \
                    xr[b] = xr[a] - tr; xi[b] = xi[a] - ti; xr[a] += tr; xi[a] += ti; }
#define BFW(a, b, Wr, Wi) { float tr = (Wr) * xr[b] - (Wi) * xi[b], ti = (Wr) * xi[b] + (Wi) * xr[b]; \
                            xr[b] = xr[a] - tr; xi[b] = xi[a] - ti; xr[a] += tr; xi[a] += ti; }
  BF1(0, 1) BF1(2, 3) BF1(4, 5) BF1(6, 7) BF1(8, 9) BF1(10, 11) BF1(12, 13) BF1(14, 15)
  BF1(0, 2) BF1(4, 6) BF1(8, 10) BF1(12, 14)
  BFI(1, 3) BFI(5, 7) BFI(9, 11) BFI(13, 15)
  BF1(0, 4) BF1(8, 12)
  BFW(1, 5, R2c, SGN * R2c) BFW(9, 13, R2c, SGN * R2c)
  BFI(2, 6) BFI(10, 14)
  BFW(3, 7, -R2c, SGN * R2c) BFW(11, 15, -R2c, SGN * R2c)
  BF1(0, 8)
  BFW(1, 9, C1c, SGN * S1cc)
  BFW(2, 10, R2c, SGN * R2c)
  BFW(3, 11, S1cc, SGN * C1c)
  BFI(4, 12)
  BFW(5, 13, -S1cc, SGN * C1c)
  BFW(6, 14, -R2c, SGN * R2c)
  BFW(7, 15, -C1c, SGN * S1cc)
#undef BF1
#undef BFI
#undef BFW
}

__global__ __launch_bounds__(256, 4) void gf5_kernel(const float* __restrict__ x,
                                                     const float* __restrict__ w,
                                                     float* __restrict__ out) {
  __shared__ __align__(8) uint32_t E[16 * IP];   // 16.5 KB, U then aliased as Q

  const int blk = blockIdx.x;
  const int ct = blk >> 8;        // 0..23  (ct-outer: W slice L2-hot)
  const int b  = blk & 255;
  const int c0 = ct * CT;
  const int t  = threadIdx.x;
  const int r  = t >> 4;          // i (S1) / n1 (S3)
  const int p  = t & 15;          // channel-pair index

  // ---------------- S1: rfft over j, 2 channels packed ----------------
  {
    const float2* xp = (const float2*)(x + (size_t)b * 196608 + (size_t)r * 12288 + c0) + p;
    float zr[16], zi[16];
#pragma unroll
    for (int j = 0; j < 16; j++) { float2 v = xp[j * 384]; zr[j] = v.x; zi[j] = v.y; }
    fft16<-1>(zr, zi);
    // slot 0: (F_a[0], F_a[8]) , (F_b[0], F_b[8])  (1x scale)
    {
      uint2 v; v.x = packh2(zr[0], zr[8]); v.y = packh2(zi[0], zi[8]);
      *(uint2*)&E[2 * (r * 129 + p)] = v;
    }
    // slots k=1..7: doubled half-spectra A'=2*F_a, B'=2*F_b
#pragma unroll
    for (int k = 1; k <= 7; k++) {
      const int m = 16 - k;
      float Ar = zr[k] + zr[m], Ai = zi[k] - zi[m];
      float Br = zi[k] + zi[m], Bi = zr[m] - zr[k];
      uint2 v; v.x = packh2(Ar, Ai); v.y = packh2(Br, Bi);
      *(uint2*)&E[2 * (r * 129 + k * 16 + p)] = v;
    }
  }
  __syncthreads();

  // ---------------- S2: fft over i, weight, ifft over k1 ----------------
  {
    const int s = t >> 5;         // slot 0..7
    const int c = t & 31;         // channel within tile
    float gr[16], gi[16];
    const uint32_t* col = E + s * 32 + c;
#pragma unroll
    for (int i = 0; i < 16; i++) { float2 v = unpackh2(col[i * IP]); gr[i] = v.x; gi[i] = v.y; }
    __syncthreads();              // all reads of U done before Q overwrites

    if (s == 0) {
      // packed: columns k2=0 and k2=8 (real), folded weights
      fft16<-1>(gr, gi);
      const float* wc = w + (size_t)(c0 + c) * 2;   // per-k1 stride 13824 floats; +12288 for k2=8
      {
        float2 a0 = *(const float2*)(wc);
        float2 a8 = *(const float2*)(wc + 12288);
        float2 b0 = *(const float2*)(wc + 8 * 13824);
        float2 b8 = *(const float2*)(wc + 8 * 13824 + 12288);
        gr[0] = gr[0] * (a0.x * INV256);
        gi[0] = gi[0] * (a8.x * INV256);
        gr[8] = gr[8] * (b0.x * INV256);
        gi[8] = gi[8] * (b8.x * INV256);
      }
#pragma unroll
      for (int k = 1; k <= 7; k++) {
        const int m = 16 - k;
        float2 a0 = *(const float2*)(wc + (size_t)k * 13824);
        float2 m0 = *(const float2*)(wc + (size_t)m * 13824);
        float2 a8 = *(const float2*)(wc + (size_t)k * 13824 + 12288);
        float2 m8 = *(const float2*)(wc + (size_t)m * 13824 + 12288);
        float Vpr = (a0.x + m0.x + a8.x + m8.x) * INV1024;
        float Vpi = (a0.y - m0.y + a8.y - m8.y) * INV1024;
        float Vmr = (a0.x + m0.x - a8.x - m8.x) * INV1024;
        float Vmi = (a0.y - m0.y - a8.y + m8.y) * INV1024;
        float ur = gr[k], ui = gi[k], vr = gr[m], vi = gi[m];
        float nkr = ur * Vpr - ui * Vpi + vr * Vmr + vi * Vmi;
        float nki = ur * Vpi + ui * Vpr + vr * Vmi - vi * Vmr;
        float nmr = vr * Vpr + vi * Vpi + ur * Vmr - ui * Vmi;
        float nmi = vi * Vpr - vr * Vpi - ur * Vmi - ui * Vmr;
        gr[k] = nkr; gi[k] = nki; gr[m] = nmr; gi[m] = nmi;
      }
      fft16<1>(gr, gi);           // (re, im) = (Re Q[.][0], Re Q[.][8])
    } else {
      // regular: column k2 = s (stored doubled -> weight * 1/512)
      float wvr[16], wvi[16];
      const float* wp = w + (size_t)(s * 768 + c0 + c) * 2;
#pragma unroll
      for (int k1 = 0; k1 < 16; k1++) {
        float2 wv = *(const float2*)(wp + (size_t)k1 * 13824);
        wvr[k1] = wv.x * INV512; wvi[k1] = wv.y * INV512;
      }
      fft16<-1>(gr, gi);
#pragma unroll
      for (int k1 = 0; k1 < 16; k1++) {
        float yr = gr[k1] * wvr[k1] - gi[k1] * wvi[k1];
        float yi = gr[k1] * wvi[k1] + gi[k1] * wvr[k1];
        gr[k1] = yr; gi[k1] = yi;
      }
      fft16<1>(gr, gi);
    }

    uint32_t* colo = E + s * 32 + c;
#pragma unroll
    for (int n1 = 0; n1 < 16; n1++) { colo[n1 * IP] = packh2(gr[n1], gi[n1]); }
  }
  __syncthreads();

  // ---------------- S3: irfft over k2, 2 channels packed, store ----------------
  {
    float hr[16], hq[16];
#pragma unroll
    for (int k = 0; k <= 7; k++) {
      uint2 v = *(const uint2*)&E[2 * (r * 129 + k * 16 + p)];
      float2 lo = unpackh2(v.x);   // (a.re, a.im)  /  k=0: (Q0_a, Q8_a)
      float2 hi = unpackh2(v.y);   // (b.re, b.im)  /  k=0: (Q0_b, Q8_b)
      if (k == 0) {
        hr[0] = lo.x; hq[0] = hi.x;
        hr[8] = lo.y; hq[8] = hi.y;
      } else {
        hr[k] = lo.x - hi.y;      hq[k] = lo.y + hi.x;
        hr[16 - k] = lo.x + hi.y; hq[16 - k] = hi.x - lo.y;
      }
    }
    fft16<1>(hr, hq);   // (re, im) = (out_a[n2], out_b[n2])
    float2* op = (float2*)(out + (size_t)b * 196608 + (size_t)r * 12288 + c0) + p;
#pragma unroll
    for (int n2 = 0; n2 < 16; n2++) { op[n2 * 384] = make_float2(hr[n2], hq[n2]); }
  }
}

extern "C" void kernel_launch(void* const* d_in, const int* in_sizes, int n_in,
                              void* d_out, int out_size, void* d_ws, size_t ws_size,
                              hipStream_t stream) {
  const float* x = (const float*)d_in[0];
  const float* w = (const float*)d_in[1];
  float* out = (float*)d_out;
  dim3 grid(NCT * 256);   // 24 * 256 = 6144
  dim3 block(256);
  hipLaunchKernelGGL(gf5_kernel, grid, block, 0, stream, x, w, out);
}